// Round 4
// baseline (109.432 us; speedup 1.0000x reference)
//
#include <hip/hip_runtime.h>
#include <math.h>

#define NB 64
#define NN 100
#define HH 128
#define HC 8
#define NCH 16

static constexpr float EPSBN = 1e-5f;

// ============ fused setup: adjacency (blocks 0-255), time MLP (256-319), vij (320) ====
__global__ __launch_bounds__(256) void k_setup(
    const float* __restrict__ X, const float* __restrict__ timev,
    const float* __restrict__ Wt1, const float* __restrict__ bt1,
    const float* __restrict__ Wt2, const float* __restrict__ bt2,
    const float* __restrict__ Wtn, const float* __restrict__ btn,
    const float* __restrict__ g_tn, const float* __restrict__ b_tn,
    const float* __restrict__ Wg1, const float* __restrict__ We0,
    const float* __restrict__ We1, const float* __restrict__ be1,
    const float* __restrict__ be0, const float* __restrict__ g_e0,
    const float* __restrict__ b_e0,
    float* __restrict__ Ah, float* __restrict__ rs,
    float* __restrict__ u1, float* __restrict__ Dfull,
    float* __restrict__ vi, float* __restrict__ vj) {
    __shared__ float sBuf[NN * NN];
    __shared__ float sdinv[128];
    const int bx = blockIdx.x, t = threadIdx.x;
    const float rinv = 1.0f / sqrtf(1.f + EPSBN);

    if (bx < 4 * NB) {
        // ---- adjacency: block (b, s) writes rows [25s, 25s+25) of Ah + rs ----
        const int b = bx >> 2, s = bx & 3;
        const float* Xb = X + b * NN * NN;
        float4* s4 = (float4*)sBuf;
        const float4* X4 = (const float4*)Xb;
        for (int idx = t; idx < NN * NN / 4; idx += 256) s4[idx] = X4[idx];
        __syncthreads();
        // degree: 2 threads per row (t<200), halves of 25 float4s, shfl-merge
        if (t < 200) {
            const int row = t >> 1, h = t & 1;
            const float4* r4 = (const float4*)(sBuf + row * NN);
            float d = 0.f;
            const int qs = h ? 13 : 0, qe = h ? 25 : 13;
            for (int q = qs; q < qe; ++q) {
                float4 v = r4[q];
                d += (v.x != 0.f ? 1.f : 0.f) + (v.y != 0.f ? 1.f : 0.f) +
                     (v.z != 0.f ? 1.f : 0.f) + (v.w != 0.f ? 1.f : 0.f);
            }
            d += __shfl_xor(d, 1);
            if (h == 0) {
                if (sBuf[row * NN + row] == 0.f) d += 1.f;  // self-loop if missing
                sdinv[row] = 1.0f / sqrtf(d);
            }
        }
        __syncthreads();
        float* Ab = Ah + b * NN * NN;
        const int i0 = s * 25;
        for (int idx = t; idx < 25 * NN; idx += 256) {
            int il = idx / NN, j = idx - il * NN;
            int i = i0 + il;
            float at = (i == j) ? 1.f : (sBuf[i * NN + j] != 0.f ? 1.f : 0.f);
            Ab[i * NN + j] = sdinv[i] * at * sdinv[j];
        }
        // rs: 8 threads per row (t<200 covers 25 rows), strided cols + shfl-reduce
        if (t < 200) {
            const int rl = t >> 3, part = t & 7;
            const int i = i0 + rl;
            float ssum = 0.f;
            for (int j = part; j < NN; j += 8) {
                float at = (i == j) ? 1.f : (sBuf[i * NN + j] != 0.f ? 1.f : 0.f);
                ssum += at * sdinv[j];
            }
            ssum += __shfl_xor(ssum, 1, 8);
            ssum += __shfl_xor(ssum, 2, 8);
            ssum += __shfl_xor(ssum, 4, 8);
            if (part == 0) rs[b * NN + i] = sdinv[i] * ssum;
        }
        return;
    }
    if (bx < 4 * NB + NB) {
        // ---- time MLP ----
        const int b = bx - 4 * NB;
        float* s_temb = sBuf;
        float* s_h1 = sBuf + 128;
        float* s_h = sBuf + 256;
        float* s_tn = sBuf + 384;
        const float tt = timev[b];
        if (t < 128) {
            int k = t & 63;
            float f = expf((float)k * (-logf(10000.f) / 63.f));
            float a = tt * f;
            s_temb[t] = (t < 64) ? sinf(a) : cosf(a);
        }
        __syncthreads();
        if (t < 128) {
            float acc = bt1[t];
            for (int q = 0; q < HH; ++q) acc = fmaf(s_temb[q], Wt1[q * HH + t], acc);
            s_h1[t] = fmaxf(acc, 0.f);
        }
        __syncthreads();
        if (t < 128) {
            float acc = bt2[t];
            for (int q = 0; q < HH; ++q) acc = fmaf(s_h1[q], Wt2[q * HH + t], acc);
            s_h[t] = acc;
        }
        __syncthreads();
        if (t < NN) {
            float v = btn[t];
            for (int q = 0; q < HH; ++q) v = fmaf(s_h[q], Wtn[q * NN + t], v);
            s_tn[t] = fmaxf(fmaf(g_tn[t] * rinv, v, b_tn[t]), 0.f);
        }
        __syncthreads();
        if (t < 128) {
            float acc = 0.f;
            for (int n = 0; n < NN; ++n) acc = fmaf(s_tn[n], Wg1[(NN + n) * HH + t], acc);
            u1[b * HH + t] = acc;
        }
        if (t == 0) {
            float tp = 0.f;
            for (int q = 0; q < HH; ++q) tp = fmaf(s_h[q], We1[HH + q], tp);
            float K = 0.f;
            for (int hh = 0; hh < HH; ++hh)
                K += (be0[hh] * g_e0[hh] * rinv + b_e0[hh]) * We1[hh];
            Dfull[b] = tp + K + be1[0];
        }
        return;
    }
    // ---- vi/vj ----
    if (t < 128) {
        sBuf[t] = g_e0[t] * We1[t] * rinv;
    }
    __syncthreads();
    if (t < 128) {
        float a = 0.f, cc = 0.f;
        for (int hh = 0; hh < HH; ++hh) {
            a = fmaf(We0[t * HH + hh], sBuf[hh], a);
            cc = fmaf(We0[(HH + t) * HH + hh], sBuf[hh], cc);
        }
        vi[t] = a;
        vj[t] = cc;
    }
}

// ============ layer 1: out = relu(bn(Ah@W1tile + rs*u1 + bg1)) ============
// grid (16, 64), block 256 = (c8=t&7 -> col, ig=t>>3 -> row group); tile 4 rows x 1 col.
__global__ __launch_bounds__(256, 4) void k_l1(
    const float* __restrict__ Ah, const float* __restrict__ Wg1,
    const float* __restrict__ u1, const float* __restrict__ rs,
    const float* __restrict__ bg1, const float* __restrict__ g1,
    const float* __restrict__ bb1, float* __restrict__ out) {
    __shared__ float sZ[HC * 108];
    const int b = blockIdx.y, hc = blockIdx.x * HC;
    const int t = threadIdx.x, c8 = t & 7, ig = t >> 3;
    for (int idx = t; idx < NN * HC; idx += 256) {
        int c = idx & 7, j = idx >> 3;
        sZ[c * 108 + j] = Wg1[j * HH + hc + c];
    }
    __syncthreads();
    const float* __restrict__ Ab = Ah + b * NN * NN;
    const int r3 = (ig < 4) ? 96 + ig : ig;
    float acc0 = 0.f, acc1 = 0.f, acc2 = 0.f, acc3 = 0.f;
    float4 a0 = *(const float4*)(Ab + ig * NN);
    float4 a1 = *(const float4*)(Ab + (ig + 32) * NN);
    float4 a2 = *(const float4*)(Ab + (ig + 64) * NN);
    float4 a3 = *(const float4*)(Ab + r3 * NN);
#pragma unroll 1
    for (int j = 0; j < NN; j += 4) {
        const int jn = (j + 4 < NN) ? j + 4 : 0;
        float4 b0 = *(const float4*)(Ab + ig * NN + jn);
        float4 b1 = *(const float4*)(Ab + (ig + 32) * NN + jn);
        float4 b2 = *(const float4*)(Ab + (ig + 64) * NN + jn);
        float4 b3 = *(const float4*)(Ab + r3 * NN + jn);
        float4 z = *(const float4*)&sZ[c8 * 108 + j];
        acc0 = fmaf(a0.x, z.x, acc0); acc0 = fmaf(a0.y, z.y, acc0);
        acc0 = fmaf(a0.z, z.z, acc0); acc0 = fmaf(a0.w, z.w, acc0);
        acc1 = fmaf(a1.x, z.x, acc1); acc1 = fmaf(a1.y, z.y, acc1);
        acc1 = fmaf(a1.z, z.z, acc1); acc1 = fmaf(a1.w, z.w, acc1);
        acc2 = fmaf(a2.x, z.x, acc2); acc2 = fmaf(a2.y, z.y, acc2);
        acc2 = fmaf(a2.z, z.z, acc2); acc2 = fmaf(a2.w, z.w, acc2);
        acc3 = fmaf(a3.x, z.x, acc3); acc3 = fmaf(a3.y, z.y, acc3);
        acc3 = fmaf(a3.z, z.z, acc3); acc3 = fmaf(a3.w, z.w, acc3);
        a0 = b0; a1 = b1; a2 = b2; a3 = b3;
    }
    const float rinv = 1.0f / sqrtf(1.f + EPSBN);
    const int h = hc + c8;
    const float gs = g1[h] * rinv, bv = bb1[h], bg = bg1[h];
    const float uh = u1[b * HH + h];
    float* ob = out + b * NN * HH;
    float accs[4] = {acc0, acc1, acc2, acc3};
#pragma unroll
    for (int q = 0; q < 4; ++q) {
        const int i = (q == 3) ? r3 : ig + 32 * q;
        if ((q < 3) || (ig < 4)) {
            float y = fmaxf(fmaf(gs, accs[q] + rs[b * NN + i] * uh + bg, bv), 0.f);
            ob[i * HH + h] = y;
        }
    }
}

// ============ fused layer: z = x@Wtile -> LDS; out = relu(bn(Ah@z + bg)) ============
template <bool LAST>
__global__ __launch_bounds__(256, 4) void k_layer(
    const float* __restrict__ Ah, const float* __restrict__ xin,
    const float* __restrict__ W, const float* __restrict__ bg,
    const float* __restrict__ g, const float* __restrict__ bb,
    const float* __restrict__ vi, const float* __restrict__ vj,
    float* __restrict__ out, float* __restrict__ psi, float* __restrict__ psj) {
    __shared__ float sW[HC * 132];
    __shared__ float sZ[HC * 108];
    const int b = blockIdx.y, hcb = blockIdx.x, hc = hcb * HC;
    const int t = threadIdx.x, c8 = t & 7, ig = t >> 3;
    for (int idx = t; idx < HH * HC; idx += 256) {
        int c = idx & 7, k = idx >> 3;
        sW[c * 132 + k] = W[k * HH + hc + c];
    }
    __syncthreads();
    const float* __restrict__ xb = xin + b * NN * HH;
    const int r3 = (ig < 4) ? 96 + ig : ig;
    float acc0 = 0.f, acc1 = 0.f, acc2 = 0.f, acc3 = 0.f;
    // ---- phase 1: z = x @ W[:, hc:hc+8] ----
    {
        float4 x0 = *(const float4*)(xb + ig * HH);
        float4 x1 = *(const float4*)(xb + (ig + 32) * HH);
        float4 x2 = *(const float4*)(xb + (ig + 64) * HH);
        float4 x3 = *(const float4*)(xb + r3 * HH);
#pragma unroll 1
        for (int k = 0; k < HH; k += 4) {
            const int kn = (k + 4) & 127;
            float4 n0 = *(const float4*)(xb + ig * HH + kn);
            float4 n1 = *(const float4*)(xb + (ig + 32) * HH + kn);
            float4 n2 = *(const float4*)(xb + (ig + 64) * HH + kn);
            float4 n3 = *(const float4*)(xb + r3 * HH + kn);
            float4 w = *(const float4*)&sW[c8 * 132 + k];
            acc0 = fmaf(x0.x, w.x, acc0); acc0 = fmaf(x0.y, w.y, acc0);
            acc0 = fmaf(x0.z, w.z, acc0); acc0 = fmaf(x0.w, w.w, acc0);
            acc1 = fmaf(x1.x, w.x, acc1); acc1 = fmaf(x1.y, w.y, acc1);
            acc1 = fmaf(x1.z, w.z, acc1); acc1 = fmaf(x1.w, w.w, acc1);
            acc2 = fmaf(x2.x, w.x, acc2); acc2 = fmaf(x2.y, w.y, acc2);
            acc2 = fmaf(x2.z, w.z, acc2); acc2 = fmaf(x2.w, w.w, acc2);
            acc3 = fmaf(x3.x, w.x, acc3); acc3 = fmaf(x3.y, w.y, acc3);
            acc3 = fmaf(x3.z, w.z, acc3); acc3 = fmaf(x3.w, w.w, acc3);
            x0 = n0; x1 = n1; x2 = n2; x3 = n3;
        }
    }
    {
        float accs[4] = {acc0, acc1, acc2, acc3};
#pragma unroll
        for (int q = 0; q < 4; ++q) {
            const int i = (q == 3) ? r3 : ig + 32 * q;
            if ((q < 3) || (ig < 4)) sZ[c8 * 108 + i] = accs[q];
        }
    }
    __syncthreads();
    // ---- phase 2: out = Ah @ z ----
    acc0 = 0.f; acc1 = 0.f; acc2 = 0.f; acc3 = 0.f;
    const float* __restrict__ Ab = Ah + b * NN * NN;
    {
        float4 a0 = *(const float4*)(Ab + ig * NN);
        float4 a1 = *(const float4*)(Ab + (ig + 32) * NN);
        float4 a2 = *(const float4*)(Ab + (ig + 64) * NN);
        float4 a3 = *(const float4*)(Ab + r3 * NN);
#pragma unroll 1
        for (int j = 0; j < NN; j += 4) {
            const int jn = (j + 4 < NN) ? j + 4 : 0;
            float4 b0 = *(const float4*)(Ab + ig * NN + jn);
            float4 b1 = *(const float4*)(Ab + (ig + 32) * NN + jn);
            float4 b2 = *(const float4*)(Ab + (ig + 64) * NN + jn);
            float4 b3 = *(const float4*)(Ab + r3 * NN + jn);
            float4 z = *(const float4*)&sZ[c8 * 108 + j];
            acc0 = fmaf(a0.x, z.x, acc0); acc0 = fmaf(a0.y, z.y, acc0);
            acc0 = fmaf(a0.z, z.z, acc0); acc0 = fmaf(a0.w, z.w, acc0);
            acc1 = fmaf(a1.x, z.x, acc1); acc1 = fmaf(a1.y, z.y, acc1);
            acc1 = fmaf(a1.z, z.z, acc1); acc1 = fmaf(a1.w, z.w, acc1);
            acc2 = fmaf(a2.x, z.x, acc2); acc2 = fmaf(a2.y, z.y, acc2);
            acc2 = fmaf(a2.z, z.z, acc2); acc2 = fmaf(a2.w, z.w, acc2);
            acc3 = fmaf(a3.x, z.x, acc3); acc3 = fmaf(a3.y, z.y, acc3);
            acc3 = fmaf(a3.z, z.z, acc3); acc3 = fmaf(a3.w, z.w, acc3);
            a0 = b0; a1 = b1; a2 = b2; a3 = b3;
        }
    }
    const float rinv = 1.0f / sqrtf(1.f + EPSBN);
    const int h = hc + c8;
    const float gs = g[h] * rinv, bv = bb[h], bgh = bg[h];
    float vih = 0.f, vjh = 0.f;
    if (LAST) { vih = vi[h]; vjh = vj[h]; }
    float* ob = LAST ? nullptr : out + b * NN * HH;
    float accs[4] = {acc0, acc1, acc2, acc3};
#pragma unroll
    for (int q = 0; q < 4; ++q) {
        const int i = (q == 3) ? r3 : ig + 32 * q;
        const bool valid = (q < 3) || (ig < 4);
        float y = fmaxf(fmaf(gs, accs[q] + bgh, bv), 0.f);
        if (LAST) {
            float pi = y * vih;
            float pj = y * vjh;
            pi += __shfl_xor(pi, 1, 8);
            pi += __shfl_xor(pi, 2, 8);
            pi += __shfl_xor(pi, 4, 8);
            pj += __shfl_xor(pj, 1, 8);
            pj += __shfl_xor(pj, 2, 8);
            pj += __shfl_xor(pj, 4, 8);
            if (c8 == 0 && valid) {
                psi[(b * NN + i) * NCH + hcb] = pi;
                psj[(b * NN + i) * NCH + hcb] = pj;
            }
        } else if (valid) {
            ob[i * HH + h] = y;
        }
    }
}

// ============ out[b,i,j] = (i!=j) * bn(si+sj+D) ============
__global__ __launch_bounds__(256) void k_out(
    const float* __restrict__ psi, const float* __restrict__ psj,
    const float* __restrict__ Dfull, const float* __restrict__ g_e1,
    const float* __restrict__ b_e1, float* __restrict__ outp) {
    __shared__ float ssi[25], ssj[NN];
    const int b = blockIdx.y, i0 = blockIdx.x * 25;
    const int t = threadIdx.x;
    if (t < NN) {
        float s = 0.f;
        const float4* p = (const float4*)(psj + (b * NN + t) * NCH);
#pragma unroll
        for (int q = 0; q < NCH / 4; ++q) {
            float4 v = p[q];
            s += v.x + v.y + v.z + v.w;
        }
        ssj[t] = s;
    }
    if (t >= 128 && t < 128 + 25) {
        int i = t - 128;
        float s = 0.f;
        const float4* p = (const float4*)(psi + (b * NN + i0 + i) * NCH);
#pragma unroll
        for (int q = 0; q < NCH / 4; ++q) {
            float4 v = p[q];
            s += v.x + v.y + v.z + v.w;
        }
        ssi[i] = s;
    }
    __syncthreads();
    const float rinv = 1.0f / sqrtf(1.f + EPSBN);
    const float D = Dfull[b], ge = g_e1[0] * rinv, be = b_e1[0];
    float* ob = outp + b * NN * NN + i0 * NN;
    for (int e = t; e < 25 * NN; e += 256) {
        int ii = e / NN, j = e - ii * NN;
        float v = fmaf(ge, ssi[ii] + ssj[j] + D, be);
        ob[e] = (i0 + ii == j) ? 0.f : v;
    }
}

extern "C" void kernel_launch(void* const* d_in, const int* in_sizes, int n_in,
                              void* d_out, int out_size, void* d_ws, size_t ws_size,
                              hipStream_t stream) {
    const float* X    = (const float*)d_in[0];
    const float* timev= (const float*)d_in[1];
    const float* Wt1  = (const float*)d_in[2];
    const float* bt1  = (const float*)d_in[3];
    const float* Wt2  = (const float*)d_in[4];
    const float* bt2  = (const float*)d_in[5];
    const float* Wtn  = (const float*)d_in[6];
    const float* btn  = (const float*)d_in[7];
    const float* g_tn = (const float*)d_in[8];
    const float* b_tn = (const float*)d_in[9];
    const float* Wg1  = (const float*)d_in[10];
    const float* bg1  = (const float*)d_in[11];
    const float* g1   = (const float*)d_in[12];
    const float* bb1  = (const float*)d_in[13];
    const float* Wg2  = (const float*)d_in[14];
    const float* bg2  = (const float*)d_in[15];
    const float* g2   = (const float*)d_in[16];
    const float* bb2  = (const float*)d_in[17];
    const float* Wg3  = (const float*)d_in[18];
    const float* bg3  = (const float*)d_in[19];
    const float* g3   = (const float*)d_in[20];
    const float* bb3  = (const float*)d_in[21];
    const float* We0  = (const float*)d_in[22];
    const float* be0  = (const float*)d_in[23];
    const float* g_e0 = (const float*)d_in[24];
    const float* b_e0 = (const float*)d_in[25];
    const float* We1  = (const float*)d_in[26];
    const float* be1  = (const float*)d_in[27];
    const float* g_e1 = (const float*)d_in[28];
    const float* b_e1 = (const float*)d_in[29];

    float* ws = (float*)d_ws;
    float* Ah    = ws;            // 640000
    float* rs    = Ah + 640000;   // 6400
    float* u1    = rs + 6400;     // 8192
    float* Dfull = u1 + 8192;     // 64
    float* vi    = Dfull + 64;    // 128
    float* vj    = vi + 128;      // 128
    float* x1    = vj + 128;      // 819200 (dead after layer2 -> psi/psj alias)
    float* x2    = x1 + 819200;   // 819200
    float* psi   = x1;            // 102400
    float* psj   = x1 + 102400;   // 102400

    k_setup<<<dim3(4 * NB + NB + 1), dim3(256), 0, stream>>>(
        X, timev, Wt1, bt1, Wt2, bt2, Wtn, btn, g_tn, b_tn, Wg1, We0, We1, be1,
        be0, g_e0, b_e0, Ah, rs, u1, Dfull, vi, vj);

    k_l1<<<dim3(NCH, NB), dim3(256), 0, stream>>>(Ah, Wg1, u1, rs, bg1, g1, bb1, x1);
    k_layer<false><<<dim3(NCH, NB), dim3(256), 0, stream>>>(Ah, x1, Wg2, bg2, g2, bb2,
                                                            nullptr, nullptr, x2,
                                                            nullptr, nullptr);
    k_layer<true><<<dim3(NCH, NB), dim3(256), 0, stream>>>(Ah, x2, Wg3, bg3, g3, bb3,
                                                           vi, vj, nullptr, psi, psj);

    k_out<<<dim3(4, NB), dim3(256), 0, stream>>>(psi, psj, Dfull, g_e1, b_e1,
                                                 (float*)d_out);
}

// Round 5
// 79.376 us; speedup vs baseline: 1.3787x; 1.3787x over previous
//
#include <hip/hip_runtime.h>
#include <math.h>

#define NB 64
#define NN 100
#define HH 128
#define HC 16
#define NCH 8

static constexpr float EPSBN = 1e-5f;

// ============ fused setup: adjacency (blocks 0-255), time MLP (256-319), vij (320) ====
// XCD-aligned decode: adjacency b = bx & 63 (so bid%8 == b%8 matches layer kernels).
__global__ __launch_bounds__(256) void k_setup(
    const float* __restrict__ X, const float* __restrict__ timev,
    const float* __restrict__ Wt1, const float* __restrict__ bt1,
    const float* __restrict__ Wt2, const float* __restrict__ bt2,
    const float* __restrict__ Wtn, const float* __restrict__ btn,
    const float* __restrict__ g_tn, const float* __restrict__ b_tn,
    const float* __restrict__ Wg1, const float* __restrict__ We0,
    const float* __restrict__ We1, const float* __restrict__ be1,
    const float* __restrict__ be0, const float* __restrict__ g_e0,
    const float* __restrict__ b_e0,
    float* __restrict__ Ah, float* __restrict__ rs,
    float* __restrict__ u1, float* __restrict__ Dfull,
    float* __restrict__ vi, float* __restrict__ vj) {
    __shared__ float sBuf[NN * NN];
    __shared__ float sdinv[128];
    const int bx = blockIdx.x, t = threadIdx.x;
    const float rinv = 1.0f / sqrtf(1.f + EPSBN);

    if (bx < 4 * NB) {
        // ---- adjacency: block (b, s) writes rows [25s, 25s+25) of Ah + rs ----
        const int b = bx & 63, s = bx >> 6;   // XCD-aligned: bx%8 == b%8
        const float* Xb = X + b * NN * NN;
        float4* s4 = (float4*)sBuf;
        const float4* X4 = (const float4*)Xb;
        for (int idx = t; idx < NN * NN / 4; idx += 256) s4[idx] = X4[idx];
        __syncthreads();
        // degree: 2 threads per row (t<200), halves of 25 float4s, shfl-merge
        if (t < 200) {
            const int row = t >> 1, h = t & 1;
            const float4* r4 = (const float4*)(sBuf + row * NN);
            float d = 0.f;
            const int qs = h ? 13 : 0, qe = h ? 25 : 13;
            for (int q = qs; q < qe; ++q) {
                float4 v = r4[q];
                d += (v.x != 0.f ? 1.f : 0.f) + (v.y != 0.f ? 1.f : 0.f) +
                     (v.z != 0.f ? 1.f : 0.f) + (v.w != 0.f ? 1.f : 0.f);
            }
            d += __shfl_xor(d, 1);
            if (h == 0) {
                if (sBuf[row * NN + row] == 0.f) d += 1.f;  // self-loop if missing
                sdinv[row] = 1.0f / sqrtf(d);
            }
        }
        __syncthreads();
        float* Ab = Ah + b * NN * NN;
        const int i0 = s * 25;
        for (int idx = t; idx < 25 * NN; idx += 256) {
            int il = idx / NN, j = idx - il * NN;
            int i = i0 + il;
            float at = (i == j) ? 1.f : (sBuf[i * NN + j] != 0.f ? 1.f : 0.f);
            Ab[i * NN + j] = sdinv[i] * at * sdinv[j];
        }
        // rs: 8 threads per row, strided cols + shfl-reduce
        if (t < 200) {
            const int rl = t >> 3, part = t & 7;
            const int i = i0 + rl;
            float ssum = 0.f;
            for (int j = part; j < NN; j += 8) {
                float at = (i == j) ? 1.f : (sBuf[i * NN + j] != 0.f ? 1.f : 0.f);
                ssum += at * sdinv[j];
            }
            ssum += __shfl_xor(ssum, 1, 8);
            ssum += __shfl_xor(ssum, 2, 8);
            ssum += __shfl_xor(ssum, 4, 8);
            if (part == 0) rs[b * NN + i] = sdinv[i] * ssum;
        }
        return;
    }
    if (bx < 4 * NB + NB) {
        // ---- time MLP ----  (bx-256)%8 == b%8, XCD-aligned automatically
        const int b = bx - 4 * NB;
        float* s_temb = sBuf;
        float* s_h1 = sBuf + 128;
        float* s_h = sBuf + 256;
        float* s_tn = sBuf + 384;
        const float tt = timev[b];
        if (t < 128) {
            int k = t & 63;
            float f = expf((float)k * (-logf(10000.f) / 63.f));
            float a = tt * f;
            s_temb[t] = (t < 64) ? sinf(a) : cosf(a);
        }
        __syncthreads();
        if (t < 128) {
            float acc = bt1[t];
            for (int q = 0; q < HH; ++q) acc = fmaf(s_temb[q], Wt1[q * HH + t], acc);
            s_h1[t] = fmaxf(acc, 0.f);
        }
        __syncthreads();
        if (t < 128) {
            float acc = bt2[t];
            for (int q = 0; q < HH; ++q) acc = fmaf(s_h1[q], Wt2[q * HH + t], acc);
            s_h[t] = acc;
        }
        __syncthreads();
        if (t < NN) {
            float v = btn[t];
            for (int q = 0; q < HH; ++q) v = fmaf(s_h[q], Wtn[q * NN + t], v);
            s_tn[t] = fmaxf(fmaf(g_tn[t] * rinv, v, b_tn[t]), 0.f);
        }
        __syncthreads();
        if (t < 128) {
            float acc = 0.f;
            for (int n = 0; n < NN; ++n) acc = fmaf(s_tn[n], Wg1[(NN + n) * HH + t], acc);
            u1[b * HH + t] = acc;
        }
        if (t == 0) {
            float tp = 0.f;
            for (int q = 0; q < HH; ++q) tp = fmaf(s_h[q], We1[HH + q], tp);
            float K = 0.f;
            for (int hh = 0; hh < HH; ++hh)
                K += (be0[hh] * g_e0[hh] * rinv + b_e0[hh]) * We1[hh];
            Dfull[b] = tp + K + be1[0];
        }
        return;
    }
    // ---- vi/vj ----
    if (t < 128) {
        sBuf[t] = g_e0[t] * We1[t] * rinv;
    }
    __syncthreads();
    if (t < 128) {
        float a = 0.f, cc = 0.f;
        for (int hh = 0; hh < HH; ++hh) {
            a = fmaf(We0[t * HH + hh], sBuf[hh], a);
            cc = fmaf(We0[(HH + t) * HH + hh], sBuf[hh], cc);
        }
        vi[t] = a;
        vj[t] = cc;
    }
}

// ============ layer 1: out = relu(bn(Ah@W1tile + rs*u1 + bg1)) ============
// grid (NB, NCH): b = blockIdx.x -> XCD b%8; block 256 = (c8, ig); tile 4 rows x 2 cols.
__global__ __launch_bounds__(256) void k_l1(
    const float* __restrict__ Ah, const float* __restrict__ Wg1,
    const float* __restrict__ u1, const float* __restrict__ rs,
    const float* __restrict__ bg1, const float* __restrict__ g1,
    const float* __restrict__ bb1, float* __restrict__ out) {
    __shared__ float sZ[HC * 108];
    const int b = blockIdx.x, hc = blockIdx.y * HC;
    const int t = threadIdx.x, c8 = t & 7, ig = t >> 3;
    {
        const int c = t & 15, j0 = t >> 4;
        for (int j = j0; j < NN; j += 16) sZ[c * 108 + j] = Wg1[j * HH + hc + c];
    }
    __syncthreads();
    const float* __restrict__ Ab = Ah + b * NN * NN;
    const int r3 = (ig < 4) ? 96 + ig : ig;
    float acc[4][2];
#pragma unroll
    for (int q = 0; q < 4; ++q) { acc[q][0] = 0.f; acc[q][1] = 0.f; }
    for (int j = 0; j < NN; j += 4) {
        float4 z0 = *(const float4*)&sZ[c8 * 108 + j];
        float4 z1 = *(const float4*)&sZ[(c8 + 8) * 108 + j];
        float4 av[4];
        av[0] = *(const float4*)(Ab + ig * NN + j);
        av[1] = *(const float4*)(Ab + (ig + 32) * NN + j);
        av[2] = *(const float4*)(Ab + (ig + 64) * NN + j);
        av[3] = *(const float4*)(Ab + r3 * NN + j);
#pragma unroll
        for (int q = 0; q < 4; ++q) {
            acc[q][0] = fmaf(av[q].x, z0.x, acc[q][0]);
            acc[q][0] = fmaf(av[q].y, z0.y, acc[q][0]);
            acc[q][0] = fmaf(av[q].z, z0.z, acc[q][0]);
            acc[q][0] = fmaf(av[q].w, z0.w, acc[q][0]);
            acc[q][1] = fmaf(av[q].x, z1.x, acc[q][1]);
            acc[q][1] = fmaf(av[q].y, z1.y, acc[q][1]);
            acc[q][1] = fmaf(av[q].z, z1.z, acc[q][1]);
            acc[q][1] = fmaf(av[q].w, z1.w, acc[q][1]);
        }
    }
    const float rinv = 1.0f / sqrtf(1.f + EPSBN);
    const int h0 = hc + c8, h1 = hc + c8 + 8;
    const float gs0 = g1[h0] * rinv, gs1 = g1[h1] * rinv;
    const float bv0 = bb1[h0], bv1 = bb1[h1];
    const float bg0 = bg1[h0], bg1v = bg1[h1];
    const float u0 = u1[b * HH + h0], u1v = u1[b * HH + h1];
    float* ob = out + b * NN * HH;
#pragma unroll
    for (int q = 0; q < 4; ++q) {
        const int i = (q == 3) ? r3 : ig + 32 * q;
        if ((q < 3) || (ig < 4)) {
            float rsv = rs[b * NN + i];
            float y0 = fmaxf(fmaf(gs0, acc[q][0] + rsv * u0 + bg0, bv0), 0.f);
            float y1 = fmaxf(fmaf(gs1, acc[q][1] + rsv * u1v + bg1v, bv1), 0.f);
            ob[i * HH + h0] = y0;
            ob[i * HH + h1] = y1;
        }
    }
}

// ============ fused layer: z = x@Wtile -> LDS; out = relu(bn(Ah@z + bg)) ============
template <bool LAST>
__global__ __launch_bounds__(256) void k_layer(
    const float* __restrict__ Ah, const float* __restrict__ xin,
    const float* __restrict__ W, const float* __restrict__ bg,
    const float* __restrict__ g, const float* __restrict__ bb,
    const float* __restrict__ vi, const float* __restrict__ vj,
    float* __restrict__ out, float* __restrict__ psi, float* __restrict__ psj) {
    __shared__ float sW[HC * 132];
    __shared__ float sZ[HC * 108];
    const int b = blockIdx.x, hcb = blockIdx.y, hc = hcb * HC;
    const int t = threadIdx.x, c8 = t & 7, ig = t >> 3;
    {
        const int c = t & 15, k0 = t >> 4;
        for (int k = k0; k < HH; k += 16) sW[c * 132 + k] = W[k * HH + hc + c];
    }
    __syncthreads();
    const float* __restrict__ xb = xin + b * NN * HH;
    const int r3 = (ig < 4) ? 96 + ig : ig;
    float acc[4][2];
#pragma unroll
    for (int q = 0; q < 4; ++q) { acc[q][0] = 0.f; acc[q][1] = 0.f; }
    for (int k = 0; k < HH; k += 4) {
        float4 w0 = *(const float4*)&sW[c8 * 132 + k];
        float4 w1 = *(const float4*)&sW[(c8 + 8) * 132 + k];
        float4 xv[4];
        xv[0] = *(const float4*)(xb + ig * HH + k);
        xv[1] = *(const float4*)(xb + (ig + 32) * HH + k);
        xv[2] = *(const float4*)(xb + (ig + 64) * HH + k);
        xv[3] = *(const float4*)(xb + r3 * HH + k);
#pragma unroll
        for (int q = 0; q < 4; ++q) {
            acc[q][0] = fmaf(xv[q].x, w0.x, acc[q][0]);
            acc[q][0] = fmaf(xv[q].y, w0.y, acc[q][0]);
            acc[q][0] = fmaf(xv[q].z, w0.z, acc[q][0]);
            acc[q][0] = fmaf(xv[q].w, w0.w, acc[q][0]);
            acc[q][1] = fmaf(xv[q].x, w1.x, acc[q][1]);
            acc[q][1] = fmaf(xv[q].y, w1.y, acc[q][1]);
            acc[q][1] = fmaf(xv[q].z, w1.z, acc[q][1]);
            acc[q][1] = fmaf(xv[q].w, w1.w, acc[q][1]);
        }
    }
#pragma unroll
    for (int q = 0; q < 4; ++q) {
        const int i = (q == 3) ? r3 : ig + 32 * q;
        if ((q < 3) || (ig < 4)) {
            sZ[c8 * 108 + i] = acc[q][0];
            sZ[(c8 + 8) * 108 + i] = acc[q][1];
        }
    }
    __syncthreads();
#pragma unroll
    for (int q = 0; q < 4; ++q) { acc[q][0] = 0.f; acc[q][1] = 0.f; }
    const float* __restrict__ Ab = Ah + b * NN * NN;
    for (int j = 0; j < NN; j += 4) {
        float4 z0 = *(const float4*)&sZ[c8 * 108 + j];
        float4 z1 = *(const float4*)&sZ[(c8 + 8) * 108 + j];
        float4 av[4];
        av[0] = *(const float4*)(Ab + ig * NN + j);
        av[1] = *(const float4*)(Ab + (ig + 32) * NN + j);
        av[2] = *(const float4*)(Ab + (ig + 64) * NN + j);
        av[3] = *(const float4*)(Ab + r3 * NN + j);
#pragma unroll
        for (int q = 0; q < 4; ++q) {
            acc[q][0] = fmaf(av[q].x, z0.x, acc[q][0]);
            acc[q][0] = fmaf(av[q].y, z0.y, acc[q][0]);
            acc[q][0] = fmaf(av[q].z, z0.z, acc[q][0]);
            acc[q][0] = fmaf(av[q].w, z0.w, acc[q][0]);
            acc[q][1] = fmaf(av[q].x, z1.x, acc[q][1]);
            acc[q][1] = fmaf(av[q].y, z1.y, acc[q][1]);
            acc[q][1] = fmaf(av[q].z, z1.z, acc[q][1]);
            acc[q][1] = fmaf(av[q].w, z1.w, acc[q][1]);
        }
    }
    const float rinv = 1.0f / sqrtf(1.f + EPSBN);
    const int h0 = hc + c8, h1 = hc + c8 + 8;
    const float gs0 = g[h0] * rinv, gs1 = g[h1] * rinv;
    const float bv0 = bb[h0], bv1 = bb[h1];
    const float bg0 = bg[h0], bg1v = bg[h1];
    float vih0 = 0.f, vih1 = 0.f, vjh0 = 0.f, vjh1 = 0.f;
    if (LAST) { vih0 = vi[h0]; vih1 = vi[h1]; vjh0 = vj[h0]; vjh1 = vj[h1]; }
    float* ob = LAST ? nullptr : out + b * NN * HH;
#pragma unroll
    for (int q = 0; q < 4; ++q) {
        const int i = (q == 3) ? r3 : ig + 32 * q;
        const bool valid = (q < 3) || (ig < 4);
        float y0 = fmaxf(fmaf(gs0, acc[q][0] + bg0, bv0), 0.f);
        float y1 = fmaxf(fmaf(gs1, acc[q][1] + bg1v, bv1), 0.f);
        if (LAST) {
            float pi = fmaf(y0, vih0, y1 * vih1);
            float pj = fmaf(y0, vjh0, y1 * vjh1);
            pi += __shfl_xor(pi, 1, 8);
            pi += __shfl_xor(pi, 2, 8);
            pi += __shfl_xor(pi, 4, 8);
            pj += __shfl_xor(pj, 1, 8);
            pj += __shfl_xor(pj, 2, 8);
            pj += __shfl_xor(pj, 4, 8);
            if (c8 == 0 && valid) {
                psi[(b * NN + i) * NCH + hcb] = pi;
                psj[(b * NN + i) * NCH + hcb] = pj;
            }
        } else if (valid) {
            ob[i * HH + h0] = y0;
            ob[i * HH + h1] = y1;
        }
    }
}

// ============ out[b,i,j] = (i!=j) * bn(si+sj+D) ============
// grid (NB, 4): b = blockIdx.x -> XCD b%8 (reads psi/psj written on same XCD).
__global__ __launch_bounds__(256) void k_out(
    const float* __restrict__ psi, const float* __restrict__ psj,
    const float* __restrict__ Dfull, const float* __restrict__ g_e1,
    const float* __restrict__ b_e1, float* __restrict__ outp) {
    __shared__ float ssi[25], ssj[NN];
    const int b = blockIdx.x, i0 = blockIdx.y * 25;
    const int t = threadIdx.x;
    if (t < NN) {
        float s = 0.f;
        const float4* p = (const float4*)(psj + (b * NN + t) * NCH);
#pragma unroll
        for (int q = 0; q < NCH / 4; ++q) {
            float4 v = p[q];
            s += v.x + v.y + v.z + v.w;
        }
        ssj[t] = s;
    }
    if (t >= 128 && t < 128 + 25) {
        int i = t - 128;
        float s = 0.f;
        const float4* p = (const float4*)(psi + (b * NN + i0 + i) * NCH);
#pragma unroll
        for (int q = 0; q < NCH / 4; ++q) {
            float4 v = p[q];
            s += v.x + v.y + v.z + v.w;
        }
        ssi[i] = s;
    }
    __syncthreads();
    const float rinv = 1.0f / sqrtf(1.f + EPSBN);
    const float D = Dfull[b], ge = g_e1[0] * rinv, be = b_e1[0];
    float* ob = outp + b * NN * NN + i0 * NN;
    for (int e = t; e < 25 * NN; e += 256) {
        int ii = e / NN, j = e - ii * NN;
        float v = fmaf(ge, ssi[ii] + ssj[j] + D, be);
        ob[e] = (i0 + ii == j) ? 0.f : v;
    }
}

extern "C" void kernel_launch(void* const* d_in, const int* in_sizes, int n_in,
                              void* d_out, int out_size, void* d_ws, size_t ws_size,
                              hipStream_t stream) {
    const float* X    = (const float*)d_in[0];
    const float* timev= (const float*)d_in[1];
    const float* Wt1  = (const float*)d_in[2];
    const float* bt1  = (const float*)d_in[3];
    const float* Wt2  = (const float*)d_in[4];
    const float* bt2  = (const float*)d_in[5];
    const float* Wtn  = (const float*)d_in[6];
    const float* btn  = (const float*)d_in[7];
    const float* g_tn = (const float*)d_in[8];
    const float* b_tn = (const float*)d_in[9];
    const float* Wg1  = (const float*)d_in[10];
    const float* bg1  = (const float*)d_in[11];
    const float* g1   = (const float*)d_in[12];
    const float* bb1  = (const float*)d_in[13];
    const float* Wg2  = (const float*)d_in[14];
    const float* bg2  = (const float*)d_in[15];
    const float* g2   = (const float*)d_in[16];
    const float* bb2  = (const float*)d_in[17];
    const float* Wg3  = (const float*)d_in[18];
    const float* bg3  = (const float*)d_in[19];
    const float* g3   = (const float*)d_in[20];
    const float* bb3  = (const float*)d_in[21];
    const float* We0  = (const float*)d_in[22];
    const float* be0  = (const float*)d_in[23];
    const float* g_e0 = (const float*)d_in[24];
    const float* b_e0 = (const float*)d_in[25];
    const float* We1  = (const float*)d_in[26];
    const float* be1  = (const float*)d_in[27];
    const float* g_e1 = (const float*)d_in[28];
    const float* b_e1 = (const float*)d_in[29];

    float* ws = (float*)d_ws;
    float* Ah    = ws;            // 640000
    float* rs    = Ah + 640000;   // 6400
    float* u1    = rs + 6400;     // 8192
    float* Dfull = u1 + 8192;     // 64
    float* vi    = Dfull + 64;    // 128
    float* vj    = vi + 128;      // 128
    float* x1    = vj + 128;      // 819200 (dead after layer2 -> psi/psj alias)
    float* x2    = x1 + 819200;   // 819200
    float* psi   = x1;            // 51200
    float* psj   = x1 + 51200;    // 51200

    k_setup<<<dim3(4 * NB + NB + 1), dim3(256), 0, stream>>>(
        X, timev, Wt1, bt1, Wt2, bt2, Wtn, btn, g_tn, b_tn, Wg1, We0, We1, be1,
        be0, g_e0, b_e0, Ah, rs, u1, Dfull, vi, vj);

    // XCD-aligned grids: batch is the fast blockIdx dim -> XCD = b%8 everywhere.
    k_l1<<<dim3(NB, NCH), dim3(256), 0, stream>>>(Ah, Wg1, u1, rs, bg1, g1, bb1, x1);
    k_layer<false><<<dim3(NB, NCH), dim3(256), 0, stream>>>(Ah, x1, Wg2, bg2, g2, bb2,
                                                            nullptr, nullptr, x2,
                                                            nullptr, nullptr);
    k_layer<true><<<dim3(NB, NCH), dim3(256), 0, stream>>>(Ah, x2, Wg3, bg3, g3, bb3,
                                                           vi, vj, nullptr, psi, psj);

    k_out<<<dim3(NB, 4), dim3(256), 0, stream>>>(psi, psj, Dfull, g_e1, b_e1,
                                                 (float*)d_out);
}

// Round 7
// 54.858 us; speedup vs baseline: 1.9948x; 1.4469x over previous
//
#include <hip/hip_runtime.h>
#include <math.h>

#define NB 64
#define NN 100
#define HH 128
#define HC 16
#define NCH 8

static constexpr float EPSBN = 1e-5f;

// ============ fused setup: adjacency (blocks 0-255), time MLP (256-319), vij (320) ====
// XCD-aligned decode: adjacency b = bx & 63 (bid%8 == b%8 matches layer kernels).
__global__ __launch_bounds__(256) void k_setup(
    const float* __restrict__ X, const float* __restrict__ timev,
    const float* __restrict__ Wt1, const float* __restrict__ bt1,
    const float* __restrict__ Wt2, const float* __restrict__ bt2,
    const float* __restrict__ Wtn, const float* __restrict__ btn,
    const float* __restrict__ g_tn, const float* __restrict__ b_tn,
    const float* __restrict__ Wg1, const float* __restrict__ We0,
    const float* __restrict__ We1, const float* __restrict__ be1,
    const float* __restrict__ be0, const float* __restrict__ g_e0,
    const float* __restrict__ b_e0,
    float* __restrict__ Ah, float* __restrict__ rs,
    float* __restrict__ u1, float* __restrict__ Dfull,
    float* __restrict__ vi, float* __restrict__ vj) {
    __shared__ float sBuf[NN * NN];
    __shared__ float sdinv[128];
    const int bx = blockIdx.x, t = threadIdx.x;
    const float rinv = 1.0f / sqrtf(1.f + EPSBN);

    if (bx < 4 * NB) {
        const int b = bx & 63, s = bx >> 6;   // XCD-aligned: bx%8 == b%8
        const float* Xb = X + b * NN * NN;
        float4* s4 = (float4*)sBuf;
        const float4* X4 = (const float4*)Xb;
        for (int idx = t; idx < NN * NN / 4; idx += 256) s4[idx] = X4[idx];
        __syncthreads();
        if (t < 200) {
            const int row = t >> 1, h = t & 1;
            const float4* r4 = (const float4*)(sBuf + row * NN);
            float d = 0.f;
            const int qs = h ? 13 : 0, qe = h ? 25 : 13;
            for (int q = qs; q < qe; ++q) {
                float4 v = r4[q];
                d += (v.x != 0.f ? 1.f : 0.f) + (v.y != 0.f ? 1.f : 0.f) +
                     (v.z != 0.f ? 1.f : 0.f) + (v.w != 0.f ? 1.f : 0.f);
            }
            d += __shfl_xor(d, 1);
            if (h == 0) {
                if (sBuf[row * NN + row] == 0.f) d += 1.f;
                sdinv[row] = 1.0f / sqrtf(d);
            }
        }
        __syncthreads();
        float* Ab = Ah + b * NN * NN;
        const int i0 = s * 25;
        for (int idx = t; idx < 25 * NN; idx += 256) {
            int il = idx / NN, j = idx - il * NN;
            int i = i0 + il;
            float at = (i == j) ? 1.f : (sBuf[i * NN + j] != 0.f ? 1.f : 0.f);
            Ab[i * NN + j] = sdinv[i] * at * sdinv[j];
        }
        if (t < 200) {
            const int rl = t >> 3, part = t & 7;
            const int i = i0 + rl;
            float ssum = 0.f;
            for (int j = part; j < NN; j += 8) {
                float at = (i == j) ? 1.f : (sBuf[i * NN + j] != 0.f ? 1.f : 0.f);
                ssum += at * sdinv[j];
            }
            ssum += __shfl_xor(ssum, 1, 8);
            ssum += __shfl_xor(ssum, 2, 8);
            ssum += __shfl_xor(ssum, 4, 8);
            if (part == 0) rs[b * NN + i] = sdinv[i] * ssum;
        }
        return;
    }
    if (bx < 4 * NB + NB) {
        const int b = bx - 4 * NB;
        float* s_temb = sBuf;
        float* s_h1 = sBuf + 128;
        float* s_h = sBuf + 256;
        float* s_tn = sBuf + 384;
        const float tt = timev[b];
        if (t < 128) {
            int k = t & 63;
            float f = expf((float)k * (-logf(10000.f) / 63.f));
            float a = tt * f;
            s_temb[t] = (t < 64) ? sinf(a) : cosf(a);
        }
        __syncthreads();
        if (t < 128) {
            float acc = bt1[t];
            for (int q = 0; q < HH; ++q) acc = fmaf(s_temb[q], Wt1[q * HH + t], acc);
            s_h1[t] = fmaxf(acc, 0.f);
        }
        __syncthreads();
        if (t < 128) {
            float acc = bt2[t];
            for (int q = 0; q < HH; ++q) acc = fmaf(s_h1[q], Wt2[q * HH + t], acc);
            s_h[t] = acc;
        }
        __syncthreads();
        if (t < NN) {
            float v = btn[t];
            for (int q = 0; q < HH; ++q) v = fmaf(s_h[q], Wtn[q * NN + t], v);
            s_tn[t] = fmaxf(fmaf(g_tn[t] * rinv, v, b_tn[t]), 0.f);
        }
        __syncthreads();
        if (t < 128) {
            float acc = 0.f;
            for (int n = 0; n < NN; ++n) acc = fmaf(s_tn[n], Wg1[(NN + n) * HH + t], acc);
            u1[b * HH + t] = acc;
        }
        if (t == 0) {
            float tp = 0.f;
            for (int q = 0; q < HH; ++q) tp = fmaf(s_h[q], We1[HH + q], tp);
            float K = 0.f;
            for (int hh = 0; hh < HH; ++hh)
                K += (be0[hh] * g_e0[hh] * rinv + b_e0[hh]) * We1[hh];
            Dfull[b] = tp + K + be1[0];
        }
        return;
    }
    if (t < 128) sBuf[t] = g_e0[t] * We1[t] * rinv;
    __syncthreads();
    if (t < 128) {
        float a = 0.f, cc = 0.f;
        for (int hh = 0; hh < HH; ++hh) {
            a = fmaf(We0[t * HH + hh], sBuf[hh], a);
            cc = fmaf(We0[(HH + t) * HH + hh], sBuf[hh], cc);
        }
        vi[t] = a;
        vj[t] = cc;
    }
}

// ================= layer 1: out = relu(bn(Ah @ Wg1[:N,hc:hc+16] + rs*u1 + bg1)) ========
// grid (NB, NCH); block 256 = (jp = t&3 j-quarter, ig = t>>2 rows {ig, 64+ig|ig<36}).
// Each thread: 2 rows x 16 cols over its j-quarter; shfl-reduce over jp. A read ONCE/block.
__global__ __launch_bounds__(256, 2) void k_l1(
    const float* __restrict__ Ah, const float* __restrict__ Wg1,
    const float* __restrict__ u1, const float* __restrict__ rs,
    const float* __restrict__ bg1, const float* __restrict__ g1,
    const float* __restrict__ bb1, float* __restrict__ out) {
    __shared__ float sZ[112 * 20];  // [j][20-pad]; rows 100..111 zeroed
    const int b = blockIdx.x, hc = blockIdx.y * HC;
    const int t = threadIdx.x, jp = t & 3, ig = t >> 2;
    for (int idx = t; idx < 400; idx += 256) {
        int j = idx >> 2, c4 = idx & 3;
        *(float4*)&sZ[j * 20 + c4 * 4] = *(const float4*)&Wg1[j * HH + hc + c4 * 4];
    }
    for (int idx = t; idx < 240; idx += 256) sZ[2000 + idx] = 0.f;
    __syncthreads();
    const int r0 = ig, r1 = (ig < 36) ? 64 + ig : ig;
    float a0[16], a1[16];
#pragma unroll
    for (int c = 0; c < 16; ++c) { a0[c] = 0.f; a1[c] = 0.f; }
    const float* __restrict__ Ab = Ah + b * NN * NN;
    const int j0 = jp * 28;
#pragma unroll
    for (int s = 0; s < 7; ++s) {
        const int j = j0 + s * 4;
        float4 v0 = *(const float4*)&Ab[r0 * NN + j];
        float4 v1 = *(const float4*)&Ab[r1 * NN + j];
#pragma unroll
        for (int jj = 0; jj < 4; ++jj) {
            const float e0 = (&v0.x)[jj], e1 = (&v1.x)[jj];
            const int zr = (j + jj) * 20;
#pragma unroll
            for (int c4 = 0; c4 < 4; ++c4) {
                float4 z = *(const float4*)&sZ[zr + c4 * 4];
                a0[c4 * 4 + 0] = fmaf(e0, z.x, a0[c4 * 4 + 0]);
                a0[c4 * 4 + 1] = fmaf(e0, z.y, a0[c4 * 4 + 1]);
                a0[c4 * 4 + 2] = fmaf(e0, z.z, a0[c4 * 4 + 2]);
                a0[c4 * 4 + 3] = fmaf(e0, z.w, a0[c4 * 4 + 3]);
                a1[c4 * 4 + 0] = fmaf(e1, z.x, a1[c4 * 4 + 0]);
                a1[c4 * 4 + 1] = fmaf(e1, z.y, a1[c4 * 4 + 1]);
                a1[c4 * 4 + 2] = fmaf(e1, z.z, a1[c4 * 4 + 2]);
                a1[c4 * 4 + 3] = fmaf(e1, z.w, a1[c4 * 4 + 3]);
            }
        }
    }
#pragma unroll
    for (int c = 0; c < 16; ++c) {
        a0[c] += __shfl_xor(a0[c], 1); a0[c] += __shfl_xor(a0[c], 2);
        a1[c] += __shfl_xor(a1[c], 1); a1[c] += __shfl_xor(a1[c], 2);
    }
    if (jp == 0) {
        const float rinv = 1.0f / sqrtf(1.f + EPSBN);
        const float rs0 = rs[b * NN + r0], rs1 = rs[b * NN + r1];
        float* ob = out + b * NN * HH;
#pragma unroll
        for (int c4 = 0; c4 < 4; ++c4) {
            float4 gv = *(const float4*)&g1[hc + c4 * 4];
            float4 bbv = *(const float4*)&bb1[hc + c4 * 4];
            float4 bgv = *(const float4*)&bg1[hc + c4 * 4];
            float4 uv = *(const float4*)&u1[b * HH + hc + c4 * 4];
            float4 y0, y1;
            y0.x = fmaxf(fmaf(gv.x * rinv, a0[c4 * 4 + 0] + rs0 * uv.x + bgv.x, bbv.x), 0.f);
            y0.y = fmaxf(fmaf(gv.y * rinv, a0[c4 * 4 + 1] + rs0 * uv.y + bgv.y, bbv.y), 0.f);
            y0.z = fmaxf(fmaf(gv.z * rinv, a0[c4 * 4 + 2] + rs0 * uv.z + bgv.z, bbv.z), 0.f);
            y0.w = fmaxf(fmaf(gv.w * rinv, a0[c4 * 4 + 3] + rs0 * uv.w + bgv.w, bbv.w), 0.f);
            y1.x = fmaxf(fmaf(gv.x * rinv, a1[c4 * 4 + 0] + rs1 * uv.x + bgv.x, bbv.x), 0.f);
            y1.y = fmaxf(fmaf(gv.y * rinv, a1[c4 * 4 + 1] + rs1 * uv.y + bgv.y, bbv.y), 0.f);
            y1.z = fmaxf(fmaf(gv.z * rinv, a1[c4 * 4 + 2] + rs1 * uv.z + bgv.z, bbv.z), 0.f);
            y1.w = fmaxf(fmaf(gv.w * rinv, a1[c4 * 4 + 3] + rs1 * uv.w + bgv.w, bbv.w), 0.f);
            *(float4*)&ob[r0 * HH + hc + c4 * 4] = y0;
            if (ig < 36) *(float4*)&ob[r1 * HH + hc + c4 * 4] = y1;
        }
    }
}

// ========= fused layer: z = x @ Wtile (k-split, shfl, ->LDS); out = Ah @ z (j-split) ====
template <bool LAST>
__global__ __launch_bounds__(256, 2) void k_layer(
    const float* __restrict__ Ah, const float* __restrict__ xin,
    const float* __restrict__ W, const float* __restrict__ bg,
    const float* __restrict__ g, const float* __restrict__ bb,
    const float* __restrict__ vi, const float* __restrict__ vj,
    float* __restrict__ out, float* __restrict__ psi, float* __restrict__ psj) {
    __shared__ float sW[128 * 16];  // [k'][16], k' = (k&31)*4 + (k>>5) (conflict-free)
    __shared__ float sZ[112 * 20];  // [j][20-pad]; rows 100..111 zeroed
    const int b = blockIdx.x, hcb = blockIdx.y, hc = hcb * HC;
    const int t = threadIdx.x, jp = t & 3, ig = t >> 2;
    for (int idx = t; idx < 512; idx += 256) {
        int k = idx >> 2, c4 = idx & 3;
        int kp = ((k & 31) << 2) | (k >> 5);
        *(float4*)&sW[kp * 16 + c4 * 4] = *(const float4*)&W[k * HH + hc + c4 * 4];
    }
    for (int idx = t; idx < 240; idx += 256) sZ[2000 + idx] = 0.f;
    __syncthreads();
    const int r0 = ig, r1 = (ig < 36) ? 64 + ig : ig;
    const float* __restrict__ xb = xin + b * NN * HH;
    float a0[16], a1[16];
#pragma unroll
    for (int c = 0; c < 16; ++c) { a0[c] = 0.f; a1[c] = 0.f; }
    // ---- phase 1: z = x @ Wtile, k in [jp*32, jp*32+32) ----
    const int wb = jp << 4;
#pragma unroll
    for (int s = 0; s < 8; ++s) {
        const int k = (jp << 5) + s * 4;
        float4 x0 = *(const float4*)&xb[r0 * HH + k];
        float4 x1 = *(const float4*)&xb[r1 * HH + k];
#pragma unroll
        for (int kk = 0; kk < 4; ++kk) {
            const float e0 = (&x0.x)[kk], e1 = (&x1.x)[kk];
            const int wr = ((s * 4 + kk) << 6) + wb;  // k'*16
#pragma unroll
            for (int c4 = 0; c4 < 4; ++c4) {
                float4 w = *(const float4*)&sW[wr + c4 * 4];
                a0[c4 * 4 + 0] = fmaf(e0, w.x, a0[c4 * 4 + 0]);
                a0[c4 * 4 + 1] = fmaf(e0, w.y, a0[c4 * 4 + 1]);
                a0[c4 * 4 + 2] = fmaf(e0, w.z, a0[c4 * 4 + 2]);
                a0[c4 * 4 + 3] = fmaf(e0, w.w, a0[c4 * 4 + 3]);
                a1[c4 * 4 + 0] = fmaf(e1, w.x, a1[c4 * 4 + 0]);
                a1[c4 * 4 + 1] = fmaf(e1, w.y, a1[c4 * 4 + 1]);
                a1[c4 * 4 + 2] = fmaf(e1, w.z, a1[c4 * 4 + 2]);
                a1[c4 * 4 + 3] = fmaf(e1, w.w, a1[c4 * 4 + 3]);
            }
        }
    }
#pragma unroll
    for (int c = 0; c < 16; ++c) {
        a0[c] += __shfl_xor(a0[c], 1); a0[c] += __shfl_xor(a0[c], 2);
        a1[c] += __shfl_xor(a1[c], 1); a1[c] += __shfl_xor(a1[c], 2);
    }
    if (jp == 0) {
#pragma unroll
        for (int c4 = 0; c4 < 4; ++c4) {
            *(float4*)&sZ[r0 * 20 + c4 * 4] =
                make_float4(a0[c4 * 4 + 0], a0[c4 * 4 + 1], a0[c4 * 4 + 2], a0[c4 * 4 + 3]);
            if (ig < 36)
                *(float4*)&sZ[r1 * 20 + c4 * 4] =
                    make_float4(a1[c4 * 4 + 0], a1[c4 * 4 + 1], a1[c4 * 4 + 2], a1[c4 * 4 + 3]);
        }
    }
    __syncthreads();
    // ---- phase 2: out = Ah @ z, j-quarter per jp ----
#pragma unroll
    for (int c = 0; c < 16; ++c) { a0[c] = 0.f; a1[c] = 0.f; }
    const float* __restrict__ Ab = Ah + b * NN * NN;
    const int j0 = jp * 28;
#pragma unroll
    for (int s = 0; s < 7; ++s) {
        const int j = j0 + s * 4;
        float4 v0 = *(const float4*)&Ab[r0 * NN + j];
        float4 v1 = *(const float4*)&Ab[r1 * NN + j];
#pragma unroll
        for (int jj = 0; jj < 4; ++jj) {
            const float e0 = (&v0.x)[jj], e1 = (&v1.x)[jj];
            const int zr = (j + jj) * 20;
#pragma unroll
            for (int c4 = 0; c4 < 4; ++c4) {
                float4 z = *(const float4*)&sZ[zr + c4 * 4];
                a0[c4 * 4 + 0] = fmaf(e0, z.x, a0[c4 * 4 + 0]);
                a0[c4 * 4 + 1] = fmaf(e0, z.y, a0[c4 * 4 + 1]);
                a0[c4 * 4 + 2] = fmaf(e0, z.z, a0[c4 * 4 + 2]);
                a0[c4 * 4 + 3] = fmaf(e0, z.w, a0[c4 * 4 + 3]);
                a1[c4 * 4 + 0] = fmaf(e1, z.x, a1[c4 * 4 + 0]);
                a1[c4 * 4 + 1] = fmaf(e1, z.y, a1[c4 * 4 + 1]);
                a1[c4 * 4 + 2] = fmaf(e1, z.z, a1[c4 * 4 + 2]);
                a1[c4 * 4 + 3] = fmaf(e1, z.w, a1[c4 * 4 + 3]);
            }
        }
    }
#pragma unroll
    for (int c = 0; c < 16; ++c) {
        a0[c] += __shfl_xor(a0[c], 1); a0[c] += __shfl_xor(a0[c], 2);
        a1[c] += __shfl_xor(a1[c], 1); a1[c] += __shfl_xor(a1[c], 2);
    }
    if (jp == 0) {
        const float rinv = 1.0f / sqrtf(1.f + EPSBN);
        float y0[16], y1[16];
#pragma unroll
        for (int c4 = 0; c4 < 4; ++c4) {
            float4 gv = *(const float4*)&g[hc + c4 * 4];
            float4 bbv = *(const float4*)&bb[hc + c4 * 4];
            float4 bgv = *(const float4*)&bg[hc + c4 * 4];
#pragma unroll
            for (int cc = 0; cc < 4; ++cc) {
                const int c = c4 * 4 + cc;
                y0[c] = fmaxf(fmaf((&gv.x)[cc] * rinv, a0[c] + (&bgv.x)[cc], (&bbv.x)[cc]), 0.f);
                y1[c] = fmaxf(fmaf((&gv.x)[cc] * rinv, a1[c] + (&bgv.x)[cc], (&bbv.x)[cc]), 0.f);
            }
        }
        if (LAST) {
            float pi0 = 0.f, pj0 = 0.f, pi1 = 0.f, pj1 = 0.f;
#pragma unroll
            for (int c = 0; c < 16; ++c) {
                const float vic = vi[hc + c], vjc = vj[hc + c];
                pi0 = fmaf(y0[c], vic, pi0); pj0 = fmaf(y0[c], vjc, pj0);
                pi1 = fmaf(y1[c], vic, pi1); pj1 = fmaf(y1[c], vjc, pj1);
            }
            psi[(b * NN + r0) * NCH + hcb] = pi0;
            psj[(b * NN + r0) * NCH + hcb] = pj0;
            if (ig < 36) {
                psi[(b * NN + r1) * NCH + hcb] = pi1;
                psj[(b * NN + r1) * NCH + hcb] = pj1;
            }
        } else {
            float* ob = out + b * NN * HH;
#pragma unroll
            for (int c4 = 0; c4 < 4; ++c4) {
                *(float4*)&ob[r0 * HH + hc + c4 * 4] =
                    make_float4(y0[c4 * 4 + 0], y0[c4 * 4 + 1], y0[c4 * 4 + 2], y0[c4 * 4 + 3]);
                if (ig < 36)
                    *(float4*)&ob[r1 * HH + hc + c4 * 4] =
                        make_float4(y1[c4 * 4 + 0], y1[c4 * 4 + 1], y1[c4 * 4 + 2], y1[c4 * 4 + 3]);
            }
        }
    }
}

// ============ out[b,i,j] = (i!=j) * bn(si+sj+D) ============
__global__ __launch_bounds__(256) void k_out(
    const float* __restrict__ psi, const float* __restrict__ psj,
    const float* __restrict__ Dfull, const float* __restrict__ g_e1,
    const float* __restrict__ b_e1, float* __restrict__ outp) {
    __shared__ float ssi[25], ssj[NN];
    const int b = blockIdx.x, i0 = blockIdx.y * 25;
    const int t = threadIdx.x;
    if (t < NN) {
        float s = 0.f;
        const float4* p = (const float4*)(psj + (b * NN + t) * NCH);
#pragma unroll
        for (int q = 0; q < NCH / 4; ++q) {
            float4 v = p[q];
            s += v.x + v.y + v.z + v.w;
        }
        ssj[t] = s;
    }
    if (t >= 128 && t < 128 + 25) {
        int i = t - 128;
        float s = 0.f;
        const float4* p = (const float4*)(psi + (b * NN + i0 + i) * NCH);
#pragma unroll
        for (int q = 0; q < NCH / 4; ++q) {
            float4 v = p[q];
            s += v.x + v.y + v.z + v.w;
        }
        ssi[i] = s;
    }
    __syncthreads();
    const float rinv = 1.0f / sqrtf(1.f + EPSBN);
    const float D = Dfull[b], ge = g_e1[0] * rinv, be = b_e1[0];
    float* ob = outp + b * NN * NN + i0 * NN;
    for (int e = t; e < 25 * NN; e += 256) {
        int ii = e / NN, j = e - ii * NN;
        float v = fmaf(ge, ssi[ii] + ssj[j] + D, be);
        ob[e] = (i0 + ii == j) ? 0.f : v;
    }
}

extern "C" void kernel_launch(void* const* d_in, const int* in_sizes, int n_in,
                              void* d_out, int out_size, void* d_ws, size_t ws_size,
                              hipStream_t stream) {
    const float* X    = (const float*)d_in[0];
    const float* timev= (const float*)d_in[1];
    const float* Wt1  = (const float*)d_in[2];
    const float* bt1  = (const float*)d_in[3];
    const float* Wt2  = (const float*)d_in[4];
    const float* bt2  = (const float*)d_in[5];
    const float* Wtn  = (const float*)d_in[6];
    const float* btn  = (const float*)d_in[7];
    const float* g_tn = (const float*)d_in[8];
    const float* b_tn = (const float*)d_in[9];
    const float* Wg1  = (const float*)d_in[10];
    const float* bg1  = (const float*)d_in[11];
    const float* g1   = (const float*)d_in[12];
    const float* bb1  = (const float*)d_in[13];
    const float* Wg2  = (const float*)d_in[14];
    const float* bg2  = (const float*)d_in[15];
    const float* g2   = (const float*)d_in[16];
    const float* bb2  = (const float*)d_in[17];
    const float* Wg3  = (const float*)d_in[18];
    const float* bg3  = (const float*)d_in[19];
    const float* g3   = (const float*)d_in[20];
    const float* bb3  = (const float*)d_in[21];
    const float* We0  = (const float*)d_in[22];
    const float* be0  = (const float*)d_in[23];
    const float* g_e0 = (const float*)d_in[24];
    const float* b_e0 = (const float*)d_in[25];
    const float* We1  = (const float*)d_in[26];
    const float* be1  = (const float*)d_in[27];
    const float* g_e1 = (const float*)d_in[28];
    const float* b_e1 = (const float*)d_in[29];

    float* ws = (float*)d_ws;
    float* Ah    = ws;            // 640000
    float* rs    = Ah + 640000;   // 6400
    float* u1    = rs + 6400;     // 8192
    float* Dfull = u1 + 8192;     // 64
    float* vi    = Dfull + 64;    // 128
    float* vj    = vi + 128;      // 128
    float* x1    = vj + 128;      // 819200 (dead after layer2 -> psi/psj alias)
    float* x2    = x1 + 819200;   // 819200
    float* psi   = x1;            // 51200
    float* psj   = x1 + 51200;    // 51200

    k_setup<<<dim3(4 * NB + NB + 1), dim3(256), 0, stream>>>(
        X, timev, Wt1, bt1, Wt2, bt2, Wtn, btn, g_tn, b_tn, Wg1, We0, We1, be1,
        be0, g_e0, b_e0, Ah, rs, u1, Dfull, vi, vj);

    // XCD-aligned grids: batch is the fast blockIdx dim -> XCD = b%8 everywhere.
    k_l1<<<dim3(NB, NCH), dim3(256), 0, stream>>>(Ah, Wg1, u1, rs, bg1, g1, bb1, x1);
    k_layer<false><<<dim3(NB, NCH), dim3(256), 0, stream>>>(Ah, x1, Wg2, bg2, g2, bb2,
                                                            nullptr, nullptr, x2,
                                                            nullptr, nullptr);
    k_layer<true><<<dim3(NB, NCH), dim3(256), 0, stream>>>(Ah, x2, Wg3, bg3, g3, bb3,
                                                           vi, vj, nullptr, psi, psj);

    k_out<<<dim3(NB, 4), dim3(256), 0, stream>>>(psi, psj, Dfull, g_e1, b_e1,
                                                 (float*)d_out);
}